// Round 18
// baseline (263.871 us; speedup 1.0000x reference)
//
#include <hip/hip_runtime.h>

#define S 64
#define ST 68    // stride (floats) for 64-col LDS tiles; rows 16B-aligned; 2-way banks free
#define STW 132  // stride for Wfc rows (128 cols + pad)
#define E_EDGES 256
#define NT 512
#define N_NODES 32768
#define NPAIRS_TOTAL 16384  // 2-node pairs across the whole node array

typedef float vf4 __attribute__((ext_vector_type(4)));  // nt-builtin-compatible 16B vector

__device__ __forceinline__ float v_rcp(float x) {
  float r;
  asm("v_rcp_f32 %0, %1" : "=v"(r) : "v"(x));
  return r;
}

// tanh(x) = 1 - 2/(exp2(2*log2e*x)+1); ~1e-7 rel err, branch-free
__device__ __forceinline__ float tanh_term(float x) {
  float t = __builtin_amdgcn_exp2f(x * 2.88539008177793f);
  return fmaf(-2.0f, v_rcp(t + 1.0f), 1.0f);
}

// zero done flags, build touched-node bitmap, compute feeder ranks:
// feeder = edge whose output a later edge consumes (must release done[] fast);
// non-feeders get contiguous ranks 0..R-1 and share the whole copy evenly.
__global__ void init_kernel(const int* __restrict__ edges, int* __restrict__ done,
                            unsigned int* __restrict__ bitmap, int* __restrict__ rankv) {
  const int tid = threadIdx.x;  // 1024 threads, 1 block
  __shared__ int feed[E_EDGES];
  if (tid < E_EDGES) done[tid] = 0;
  bitmap[tid] = 0u;
  __syncthreads();
  if (tid < 2 * E_EDGES) {
    int node = edges[tid];
    atomicOr(&bitmap[node >> 5], 1u << (node & 31));
  }
  if (tid < E_EDGES) {
    int a = edges[tid], b = edges[E_EDGES + tid];
    int f = 0;
    for (int t = tid + 1; t < E_EDGES; ++t) {
      int xa = edges[t], yb = edges[E_EDGES + t];
      if (xa == a || yb == a || xa == b || yb == b) { f = 1; break; }
    }
    feed[tid] = f;
  }
  __syncthreads();
  if (tid == 0) {
    int r = 0;
    for (int i = 0; i < E_EDGES; ++i) rankv[i] = feed[i] ? -1 : r++;
    rankv[E_EDGES] = r;  // R = non-feeder count (>=1: last edge never feeds)
  }
}

__global__ __launch_bounds__(NT, 1) void fused_kernel(
    const float* __restrict__ inputs,
    const int* __restrict__ masks,
    const int* __restrict__ edges,
    const float* __restrict__ Wq,
    const float* __restrict__ Wk,
    const float* __restrict__ wv,
    const float* __restrict__ Wfc,
    const float* __restrict__ bfc,
    float* __restrict__ out,
    int* __restrict__ done,
    const unsigned int* __restrict__ bitmap,
    const int* __restrict__ rankv) {
  const int tid = threadIdx.x;
  const int e = blockIdx.x;
  const int lane = tid & 63;
  const int wvid = tid >> 6;

  __shared__ float sWqT[S][ST];   // transposed: sWqT[j][h] = Wq[h][j]
  __shared__ float sWkT[S][ST];
  __shared__ float sWfc[S][STW];  // sWfc[h][r], r<128
  __shared__ float sEx[S][ST];
  __shared__ float sEy[S][ST];
  __shared__ float sQ[S][ST];
  __shared__ float sK[S][ST];
  __shared__ float sP[S][ST];
  __shared__ float swv[S];
  __shared__ float sbfc[S];
  __shared__ unsigned int sBitmap[N_NODES / 32];  // 4 KB
  __shared__ int sMeta[6];  // depA, depB, validA, validB, ready, pad

  const int a = edges[e];
  const int b = edges[E_EDGES + e];

  if (tid < 2) sMeta[tid] = -1;
  __syncthreads();
  // dep scan: latest earlier edge touching node a / node b
  if (tid < e) {
    int xa = edges[tid], yb = edges[E_EDGES + tid];
    if (xa == a || yb == a) atomicMax(&sMeta[0], tid);
    if (xa == b || yb == b) atomicMax(&sMeta[1], tid);
  }

  // stage weights (transposed Wq/Wk), Wfc, wv/bfc, bitmap
#pragma unroll
  for (int k = 0; k < 2; ++k) {
    int i4 = tid + k * NT;  // 0..1023
    int h = i4 >> 4, j0 = (i4 & 15) << 2;
    float4 q4 = *(const float4*)(Wq + h * S + j0);
    float4 k4 = *(const float4*)(Wk + h * S + j0);
    sWqT[j0 + 0][h] = q4.x; sWqT[j0 + 1][h] = q4.y;
    sWqT[j0 + 2][h] = q4.z; sWqT[j0 + 3][h] = q4.w;
    sWkT[j0 + 0][h] = k4.x; sWkT[j0 + 1][h] = k4.y;
    sWkT[j0 + 2][h] = k4.z; sWkT[j0 + 3][h] = k4.w;
  }
#pragma unroll
  for (int k = 0; k < 4; ++k) {
    int i4 = tid + k * NT;  // 0..2047
    int h = i4 >> 5, r0 = (i4 & 31) << 2;
    *(float4*)&sWfc[h][r0] = *(const float4*)(Wfc + h * 2 * S + r0);
  }
  if (tid < S) { swv[tid] = wv[tid]; sbfc[tid] = bfc[tid]; }
  sBitmap[tid] = bitmap[tid];
  sBitmap[tid + NT] = bitmap[tid + NT];

  // valid lengths
  int mv = 0;
  if (wvid == 0) mv = masks[(size_t)a * S + lane];
  else if (wvid == 1) mv = masks[(size_t)b * S + lane];
#pragma unroll
  for (int d = 1; d < 64; d <<= 1) mv += __shfl_xor(mv, d, 64);
  if (tid == 0) sMeta[2] = mv;
  if (tid == 64) sMeta[3] = mv;

  __syncthreads();
  const int depA = sMeta[0], depB = sMeta[1];
  const int validA = sMeta[2], validB = sMeta[3];

  // copy range from non-feeder rank (feeders: empty range, fast done-release)
  const int rk = rankv[e];
  const int R = rankv[E_EDGES];
  int g, pEnd;
  if (rk < 0) {
    g = pEnd = 0;
  } else {
    g = (NPAIRS_TOTAL * rk) / R;
    pEnd = (NPAIRS_TOTAL * (rk + 1)) / R;
  }

  // copy global pair p (nodes 2p, 2p+1): 4 nontemporal vf4 loads over a
  // contiguous 32 KB span, tight nt stores (1x HBM writes; bitmap test uniform)
  auto copy_pair = [&](int p) {
    const int n0 = 2 * p;
    const int n1 = n0 + 1;
    const size_t f4 = (size_t)n0 * 1024;
    const vf4* __restrict__ src = (const vf4*)inputs + f4;
    vf4* __restrict__ dst = (vf4*)out + f4;
    vf4 v0 = __builtin_nontemporal_load(src + tid);
    vf4 v1 = __builtin_nontemporal_load(src + tid + 512);
    vf4 v2 = __builtin_nontemporal_load(src + tid + 1024);
    vf4 v3 = __builtin_nontemporal_load(src + tid + 1536);
    if (!(sBitmap[n0 >> 5] & (1u << (n0 & 31)))) {
      __builtin_nontemporal_store(v0, dst + tid);
      __builtin_nontemporal_store(v1, dst + tid + 512);
    }
    if (!(sBitmap[n1 >> 5] & (1u << (n1 & 31)))) {
      __builtin_nontemporal_store(v2, dst + tid + 1024);
      __builtin_nontemporal_store(v3, dst + tid + 1536);
    }
  };

  // boundary copy slot: 2 tight pairs (2x 32 KB) fill the HBM-idle edge window
  auto cp2 = [&]() {
    if (g < pEnd) {
      copy_pair(g);
      if (g + 1 < pEnd) copy_pair(g + 1);
      g += 2;
    }
  };

  // dep blocks poll (RELAXED, no per-iteration invalidate); then ONE acquire per dep.
  // Blocks with a copy range copy while waiting; feeders just sleep-poll.
  if (depA >= 0 || depB >= 0) {
    for (;;) {
      __syncthreads();
      if (tid == 0) {
        int ok = 1;
        if (depA >= 0 &&
            __hip_atomic_load(&done[depA], __ATOMIC_RELAXED, __HIP_MEMORY_SCOPE_AGENT) == 0)
          ok = 0;
        if (ok && depB >= 0 &&
            __hip_atomic_load(&done[depB], __ATOMIC_RELAXED, __HIP_MEMORY_SCOPE_AGENT) == 0)
          ok = 0;
        sMeta[4] = ok;
      }
      __syncthreads();
      if (sMeta[4]) break;
      if (g < pEnd) {
        copy_pair(g);
        if (g + 1 < pEnd) copy_pair(g + 1);
        g += 2;
      } else {
        __builtin_amdgcn_s_sleep(8);
      }
    }
    if (tid == 0) {
      if (depA >= 0)
        (void)__hip_atomic_load(&done[depA], __ATOMIC_ACQUIRE, __HIP_MEMORY_SCOPE_AGENT);
      if (depB >= 0)
        (void)__hip_atomic_load(&done[depB], __ATOMIC_ACQUIRE, __HIP_MEMORY_SCOPE_AGENT);
    }
    __syncthreads();
  }

  // stage embeddings (first touch from inputs, else chain state in out)
  const float* exg = (depA >= 0) ? out + (size_t)a * 4096 : inputs + (size_t)a * 4096;
  const float* eyg = (depB >= 0) ? out + (size_t)b * 4096 : inputs + (size_t)b * 4096;
#pragma unroll
  for (int k = 0; k < 2; ++k) {
    int i4 = tid + k * NT;
    int r = i4 >> 4, c4 = (i4 & 15) << 2;
    *(float4*)&sEx[r][c4] = *(const float4*)(exg + r * S + c4);
    *(float4*)&sEy[r][c4] = *(const float4*)(eyg + r * S + c4);
  }
  __syncthreads();

  // --- thread tiling: rows {ty, ty+32}, cols c0..c0+3 ---
  const int ty = tid >> 4;  // 0..31
  const int tx = tid & 15;  // 0..15
  const int c0 = tx << 2;

  // D[i][h] = sum_j A[i][j] * WT[j][h]
  auto proj = [&](const float (*A)[ST], const float (*WT)[ST], float (*D)[ST]) {
    float acc[2][4] = {};
#pragma unroll 4
    for (int j0 = 0; j0 < S; j0 += 4) {
      float4 av[2];
      av[0] = *(const float4*)&A[ty][j0];
      av[1] = *(const float4*)&A[ty + 32][j0];
#pragma unroll
      for (int jj = 0; jj < 4; ++jj) {
        float4 w4 = *(const float4*)&WT[j0 + jj][c0];
#pragma unroll
        for (int s = 0; s < 2; ++s) {
          float as = (&av[s].x)[jj];
          acc[s][0] = fmaf(as, w4.x, acc[s][0]);
          acc[s][1] = fmaf(as, w4.y, acc[s][1]);
          acc[s][2] = fmaf(as, w4.z, acc[s][2]);
          acc[s][3] = fmaf(as, w4.w, acc[s][3]);
        }
      }
    }
    *(float4*)&D[ty][c0] = make_float4(acc[0][0], acc[0][1], acc[0][2], acc[0][3]);
    *(float4*)&D[ty + 32][c0] = make_float4(acc[1][0], acc[1][1], acc[1][2], acc[1][3]);
  };

  // scores -> sP; cols cu = tx + 16u; wave-uniform chunk skip; masked cols get 0.0f
  auto score_phase = [&](int vlen) {
    if (vlen == 0) {  // softmax of all -1e6 = uniform 1/64
#pragma unroll
      for (int u = 0; u < 4; ++u) {
        sP[ty][tx + 16 * u] = 0.015625f;
        sP[ty + 32][tx + 16 * u] = 0.015625f;
      }
      return;
    }
    float acc[2][4] = {};
#pragma unroll 2
    for (int h0 = 0; h0 < S; h0 += 4) {
      float4 q4[2];
      q4[0] = *(const float4*)&sQ[ty][h0];
      q4[1] = *(const float4*)&sQ[ty + 32][h0];
      float4 wv4 = *(const float4*)&swv[h0];
#pragma unroll
      for (int u = 0; u < 4; ++u) {
        if (16 * u < vlen) {  // wave-uniform chunk skip
          float4 k4 = *(const float4*)&sK[tx + 16 * u][h0];
#pragma unroll
          for (int jj = 0; jj < 4; ++jj) {
            float kk = (&k4.x)[jj];
            float wvh = (&wv4.x)[jj];
            acc[0][u] = fmaf(tanh_term((&q4[0].x)[jj] + kk), wvh, acc[0][u]);
            acc[1][u] = fmaf(tanh_term((&q4[1].x)[jj] + kk), wvh, acc[1][u]);
          }
        }
      }
    }
#pragma unroll
    for (int u = 0; u < 4; ++u) {
      int cu = tx + 16 * u;
      sP[ty][cu] = (cu < vlen) ? acc[0][u] : 0.0f;      // zeros feed pv tail
      sP[ty + 32][cu] = (cu < vlen) ? acc[1][u] : 0.0f;
    }
  };

  // row softmax over cols < vlen: 8 lanes per row
  auto softmax_phase = [&](int vlen) {
    if (vlen == 0) return;  // already uniform
    const int row = tid >> 3, sub = tid & 7;
    float m = -3.0e38f;
#pragma unroll
    for (int k = 0; k < 8; ++k) {
      int c = sub + 8 * k;
      if (c < vlen) m = fmaxf(m, sP[row][c]);
    }
#pragma unroll
    for (int d = 1; d < 8; d <<= 1) m = fmaxf(m, __shfl_xor(m, d, 8));
    float p[8];
    float sum = 0.f;
#pragma unroll
    for (int k = 0; k < 8; ++k) {
      int c = sub + 8 * k;
      if (c < vlen) {
        p[k] = __expf(sP[row][c] - m);
        sum += p[k];
      }
    }
#pragma unroll
    for (int d = 1; d < 8; d <<= 1) sum += __shfl_xor(sum, d, 8);
    float inv = 1.0f / sum;
#pragma unroll
    for (int k = 0; k < 8; ++k) {
      int c = sub + 8 * k;
      if (c < vlen) sP[row][c] = p[k] * inv;
    }
  };

  // D[i][j] = sum_k P[i][k] * V[k][j]; k truncated to rounded vlen (zeros beyond)
  auto pv_phase = [&](const float (*V)[ST], float (*D)[ST], int vlen) {
    const int kEnd = (vlen == 0) ? S : ((vlen + 3) & ~3);
    float acc[2][4] = {};
    for (int k0 = 0; k0 < kEnd; k0 += 4) {
      float4 p4[2];
      p4[0] = *(const float4*)&sP[ty][k0];
      p4[1] = *(const float4*)&sP[ty + 32][k0];
#pragma unroll
      for (int kk = 0; kk < 4; ++kk) {
        float4 v4 = *(const float4*)&V[k0 + kk][c0];
#pragma unroll
        for (int s = 0; s < 2; ++s) {
          float ps = (&p4[s].x)[kk];
          acc[s][0] = fmaf(ps, v4.x, acc[s][0]);
          acc[s][1] = fmaf(ps, v4.y, acc[s][1]);
          acc[s][2] = fmaf(ps, v4.z, acc[s][2]);
          acc[s][3] = fmaf(ps, v4.w, acc[s][3]);
        }
      }
    }
    *(float4*)&D[ty][c0] = make_float4(acc[0][0], acc[0][1], acc[0][2], acc[0][3]);
    *(float4*)&D[ty + 32][c0] = make_float4(acc[1][0], acc[1][1], acc[1][2], acc[1][3]);
  };

  // out[h][c] = bfc[h] + sum_r Wfc[h][r]*E1[r][c] + sum_r Wfc[h][64+r]*A1[r][c]
  auto fc_phase = [&](const float (*E1)[ST], const float (*A1)[ST], float* outg) {
    float acc[2][4];
#pragma unroll
    for (int s = 0; s < 2; ++s) {
      float bv = sbfc[ty + 32 * s];
      acc[s][0] = bv; acc[s][1] = bv; acc[s][2] = bv; acc[s][3] = bv;
    }
#pragma unroll 2
    for (int r0 = 0; r0 < S; r0 += 4) {
      float4 w4[2];
      w4[0] = *(const float4*)&sWfc[ty][r0];
      w4[1] = *(const float4*)&sWfc[ty + 32][r0];
#pragma unroll
      for (int rr = 0; rr < 4; ++rr) {
        float4 e4 = *(const float4*)&E1[r0 + rr][c0];
#pragma unroll
        for (int s = 0; s < 2; ++s) {
          float ws = (&w4[s].x)[rr];
          acc[s][0] = fmaf(ws, e4.x, acc[s][0]);
          acc[s][1] = fmaf(ws, e4.y, acc[s][1]);
          acc[s][2] = fmaf(ws, e4.z, acc[s][2]);
          acc[s][3] = fmaf(ws, e4.w, acc[s][3]);
        }
      }
    }
#pragma unroll 2
    for (int r0 = 0; r0 < S; r0 += 4) {
      float4 w4[2];
      w4[0] = *(const float4*)&sWfc[ty][S + r0];
      w4[1] = *(const float4*)&sWfc[ty + 32][S + r0];
#pragma unroll
      for (int rr = 0; rr < 4; ++rr) {
        float4 e4 = *(const float4*)&A1[r0 + rr][c0];
#pragma unroll
        for (int s = 0; s < 2; ++s) {
          float ws = (&w4[s].x)[rr];
          acc[s][0] = fmaf(ws, e4.x, acc[s][0]);
          acc[s][1] = fmaf(ws, e4.y, acc[s][1]);
          acc[s][2] = fmaf(ws, e4.z, acc[s][2]);
          acc[s][3] = fmaf(ws, e4.w, acc[s][3]);
        }
      }
    }
    *(float4*)(outg + (size_t)ty * S + c0) =
        make_float4(acc[0][0], acc[0][1], acc[0][2], acc[0][3]);
    *(float4*)(outg + (size_t)(ty + 32) * S + c0) =
        make_float4(acc[1][0], acc[1][1], acc[1][2], acc[1][3]);
  };

  // ---- attention 1: q from ex, kv = ey, vlen = valid[a] ----
  // cp2 slots fill the HBM-idle edge window (blocks with a copy range)
  proj(sEx, sWqT, sQ);
  proj(sEy, sWkT, sK);
  cp2();
  cp2();
  cp2();
  __syncthreads();
  score_phase(validA);
  cp2();
  cp2();
  cp2();
  __syncthreads();
  softmax_phase(validA);
  cp2();
  cp2();
  cp2();
  __syncthreads();
  pv_phase(sEy, sQ, validA);  // sQ := y2x
  cp2();
  cp2();
  cp2();
  __syncthreads();
  fc_phase(sEx, sQ, out + (size_t)a * 4096);
  cp2();
  __syncthreads();

  // ---- attention 2: q from ey, kv = ex, vlen = valid[b] ----
  proj(sEy, sWqT, sQ);
  proj(sEx, sWkT, sK);
  cp2();
  cp2();
  cp2();
  __syncthreads();
  score_phase(validB);
  cp2();
  cp2();
  cp2();
  __syncthreads();
  softmax_phase(validB);
  cp2();
  cp2();
  cp2();
  __syncthreads();
  pv_phase(sEx, sQ, validB);  // sQ := x2y
  cp2();
  cp2();
  cp2();
  __syncthreads();
  fc_phase(sEy, sQ, out + (size_t)b * 4096);  // y written last -> wins on self-loop

  // __syncthreads drains every wave's stores; RELEASE store orders them at agent scope
  __syncthreads();
  if (tid == 0)
    __hip_atomic_store(&done[e], 1, __ATOMIC_RELEASE, __HIP_MEMORY_SCOPE_AGENT);

  // ---- finish this block's copy range (tight streaming) ----
  for (; g < pEnd; ++g) copy_pair(g);
}

extern "C" void kernel_launch(void* const* d_in, const int* in_sizes, int n_in,
                              void* d_out, int out_size, void* d_ws, size_t ws_size,
                              hipStream_t stream) {
  const float* inputs = (const float*)d_in[0];
  const int* masks = (const int*)d_in[1];
  const int* edges = (const int*)d_in[2];
  const float* Wq = (const float*)d_in[3];
  const float* Wk = (const float*)d_in[4];
  const float* wv = (const float*)d_in[5];
  const float* Wfc = (const float*)d_in[6];
  const float* bfc = (const float*)d_in[7];
  float* out = (float*)d_out;
  int* done = (int*)d_ws;                                  // 256 ints
  unsigned int* bitmap = (unsigned int*)(done + E_EDGES);  // 1024 words
  int* rankv = (int*)(bitmap + N_NODES / 32);              // 257 ints

  init_kernel<<<1, 1024, 0, stream>>>(edges, done, bitmap, rankv);
  fused_kernel<<<E_EDGES, NT, 0, stream>>>(inputs, masks, edges, Wq, Wk, wv, Wfc,
                                           bfc, out, done, bitmap, rankv);
}

// Round 19
// 233.354 us; speedup vs baseline: 1.1308x; 1.1308x over previous
//
#include <hip/hip_runtime.h>

#define S 64
#define ST 68    // stride (floats) for 64-col LDS tiles; rows 16B-aligned; 2-way banks free
#define STW 132  // stride for Wfc rows (128 cols + pad)
#define E_EDGES 256
#define NT 512
#define N_NODES 32768
#define NPB 128    // nodes per block (static copy range)
#define NPAIRS 64  // 2-node copy groups per block

typedef float vf4 __attribute__((ext_vector_type(4)));  // nt-builtin-compatible 16B vector

__device__ __forceinline__ float v_rcp(float x) {
  float r;
  asm("v_rcp_f32 %0, %1" : "=v"(r) : "v"(x));
  return r;
}

// tanh(x) = 1 - 2/(exp2(2*log2e*x)+1); ~1e-7 rel err, branch-free
__device__ __forceinline__ float tanh_term(float x) {
  float t = __builtin_amdgcn_exp2f(x * 2.88539008177793f);
  return fmaf(-2.0f, v_rcp(t + 1.0f), 1.0f);
}

// zero done flags, build touched-node bitmap
__global__ void init_kernel(const int* __restrict__ edges, int* __restrict__ done,
                            unsigned int* __restrict__ bitmap) {
  const int tid = threadIdx.x;  // 1024 threads, 1 block
  if (tid < E_EDGES) done[tid] = 0;
  bitmap[tid] = 0u;
  __syncthreads();
  if (tid < 2 * E_EDGES) {
    int node = edges[tid];
    atomicOr(&bitmap[node >> 5], 1u << (node & 31));
  }
}

__global__ __launch_bounds__(NT, 1) void fused_kernel(
    const float* __restrict__ inputs,
    const int* __restrict__ masks,
    const int* __restrict__ edges,
    const float* __restrict__ Wq,
    const float* __restrict__ Wk,
    const float* __restrict__ wv,
    const float* __restrict__ Wfc,
    const float* __restrict__ bfc,
    float* __restrict__ out,
    int* __restrict__ done,
    const unsigned int* __restrict__ bitmap) {
  const int tid = threadIdx.x;
  const int e = blockIdx.x;
  const int lane = tid & 63;
  const int wvid = tid >> 6;

  __shared__ float sWqT[S][ST];   // transposed: sWqT[j][h] = Wq[h][j]
  __shared__ float sWkT[S][ST];
  __shared__ float sWfc[S][STW];  // sWfc[h][r], r<128
  __shared__ float sEx[S][ST];
  __shared__ float sEy[S][ST];
  __shared__ float sQ[S][ST];
  __shared__ float sK[S][ST];
  __shared__ float sP[S][ST];
  __shared__ float swv[S];
  __shared__ float sbfc[S];
  __shared__ unsigned int sBitmap[N_NODES / 32];  // 4 KB
  __shared__ int sMeta[6];  // depA, depB, validA, validB, ready, hasSucc

  const int a = edges[e];
  const int b = edges[E_EDGES + e];

  if (tid < 2) sMeta[tid] = -1;
  if (tid == 2) sMeta[5] = 0;
  __syncthreads();
  // dep scan: latest earlier edge touching node a / node b
  // feeder scan: any LATER edge touching a or b reads our output -> release fast
  if (tid < E_EDGES) {
    int xa = edges[tid], yb = edges[E_EDGES + tid];
    bool touches = (xa == a || yb == a || xa == b || yb == b);
    if (tid < e) {
      if (xa == a || yb == a) atomicMax(&sMeta[0], tid);
      if (xa == b || yb == b) atomicMax(&sMeta[1], tid);
    } else if (tid > e && touches) {
      sMeta[5] = 1;  // benign race: all writers store 1
    }
  }

  // stage weights (transposed Wq/Wk), Wfc, wv/bfc, bitmap
#pragma unroll
  for (int k = 0; k < 2; ++k) {
    int i4 = tid + k * NT;  // 0..1023
    int h = i4 >> 4, j0 = (i4 & 15) << 2;
    float4 q4 = *(const float4*)(Wq + h * S + j0);
    float4 k4 = *(const float4*)(Wk + h * S + j0);
    sWqT[j0 + 0][h] = q4.x; sWqT[j0 + 1][h] = q4.y;
    sWqT[j0 + 2][h] = q4.z; sWqT[j0 + 3][h] = q4.w;
    sWkT[j0 + 0][h] = k4.x; sWkT[j0 + 1][h] = k4.y;
    sWkT[j0 + 2][h] = k4.z; sWkT[j0 + 3][h] = k4.w;
  }
#pragma unroll
  for (int k = 0; k < 4; ++k) {
    int i4 = tid + k * NT;  // 0..2047
    int h = i4 >> 5, r0 = (i4 & 31) << 2;
    *(float4*)&sWfc[h][r0] = *(const float4*)(Wfc + h * 2 * S + r0);
  }
  if (tid < S) { swv[tid] = wv[tid]; sbfc[tid] = bfc[tid]; }
  sBitmap[tid] = bitmap[tid];
  sBitmap[tid + NT] = bitmap[tid + NT];

  // valid lengths
  int mv = 0;
  if (wvid == 0) mv = masks[(size_t)a * S + lane];
  else if (wvid == 1) mv = masks[(size_t)b * S + lane];
#pragma unroll
  for (int d = 1; d < 64; d <<= 1) mv += __shfl_xor(mv, d, 64);
  if (tid == 0) sMeta[2] = mv;
  if (tid == 64) sMeta[3] = mv;

  __syncthreads();
  const int depA = sMeta[0], depB = sMeta[1];
  const int validA = sMeta[2], validB = sMeta[3];
  const bool feeder = sMeta[5] != 0;  // later blocks wait on us -> defer copy

  // copy pair p of this block's static range: 4 nontemporal vf4 loads over a
  // contiguous 32 KB span, tight nt stores (1x HBM writes; bitmap test uniform)
  auto copy_pair = [&](int p) {
    const int n0 = e * NPB + 2 * p;
    const int n1 = n0 + 1;
    const size_t f4 = (size_t)n0 * 1024;
    const vf4* __restrict__ src = (const vf4*)inputs + f4;
    vf4* __restrict__ dst = (vf4*)out + f4;
    vf4 v0 = __builtin_nontemporal_load(src + tid);
    vf4 v1 = __builtin_nontemporal_load(src + tid + 512);
    vf4 v2 = __builtin_nontemporal_load(src + tid + 1024);
    vf4 v3 = __builtin_nontemporal_load(src + tid + 1536);
    if (!(sBitmap[n0 >> 5] & (1u << (n0 & 31)))) {
      __builtin_nontemporal_store(v0, dst + tid);
      __builtin_nontemporal_store(v1, dst + tid + 512);
    }
    if (!(sBitmap[n1 >> 5] & (1u << (n1 & 31)))) {
      __builtin_nontemporal_store(v2, dst + tid + 1024);
      __builtin_nontemporal_store(v3, dst + tid + 1536);
    }
  };

  int g = 0;  // copy progress through this block's 64 pairs
  // boundary copy slot: feeders skip (fast done-release); others fill the
  // HBM-idle edge window with 2 tight pairs per slot
  auto cp2 = [&]() {
    if (!feeder && g < NPAIRS) {
      copy_pair(g);
      copy_pair(g + 1);
      g += 2;
    }
  };

  // dep blocks poll (RELAXED, no per-iteration invalidate); then ONE acquire per dep.
  // Feeders spin without copying (minimal chain latency); others copy while waiting.
  if (depA >= 0 || depB >= 0) {
    for (;;) {
      __syncthreads();
      if (tid == 0) {
        int ok = 1;
        if (depA >= 0 &&
            __hip_atomic_load(&done[depA], __ATOMIC_RELAXED, __HIP_MEMORY_SCOPE_AGENT) == 0)
          ok = 0;
        if (ok && depB >= 0 &&
            __hip_atomic_load(&done[depB], __ATOMIC_RELAXED, __HIP_MEMORY_SCOPE_AGENT) == 0)
          ok = 0;
        sMeta[4] = ok;
      }
      __syncthreads();
      if (sMeta[4]) break;
      if (!feeder && g < NPAIRS) {
        copy_pair(g);
        copy_pair(g + 1);
        g += 2;
      } else {
        __builtin_amdgcn_s_sleep(8);
      }
    }
    if (tid == 0) {
      if (depA >= 0)
        (void)__hip_atomic_load(&done[depA], __ATOMIC_ACQUIRE, __HIP_MEMORY_SCOPE_AGENT);
      if (depB >= 0)
        (void)__hip_atomic_load(&done[depB], __ATOMIC_ACQUIRE, __HIP_MEMORY_SCOPE_AGENT);
    }
    __syncthreads();
  }

  // stage embeddings (first touch from inputs, else chain state in out)
  const float* exg = (depA >= 0) ? out + (size_t)a * 4096 : inputs + (size_t)a * 4096;
  const float* eyg = (depB >= 0) ? out + (size_t)b * 4096 : inputs + (size_t)b * 4096;
#pragma unroll
  for (int k = 0; k < 2; ++k) {
    int i4 = tid + k * NT;
    int r = i4 >> 4, c4 = (i4 & 15) << 2;
    *(float4*)&sEx[r][c4] = *(const float4*)(exg + r * S + c4);
    *(float4*)&sEy[r][c4] = *(const float4*)(eyg + r * S + c4);
  }
  __syncthreads();

  // --- thread tiling: rows {ty, ty+32}, cols c0..c0+3 ---
  const int ty = tid >> 4;  // 0..31
  const int tx = tid & 15;  // 0..15
  const int c0 = tx << 2;

  // D[i][h] = sum_j A[i][j] * WT[j][h]
  auto proj = [&](const float (*A)[ST], const float (*WT)[ST], float (*D)[ST]) {
    float acc[2][4] = {};
#pragma unroll 4
    for (int j0 = 0; j0 < S; j0 += 4) {
      float4 av[2];
      av[0] = *(const float4*)&A[ty][j0];
      av[1] = *(const float4*)&A[ty + 32][j0];
#pragma unroll
      for (int jj = 0; jj < 4; ++jj) {
        float4 w4 = *(const float4*)&WT[j0 + jj][c0];
#pragma unroll
        for (int s = 0; s < 2; ++s) {
          float as = (&av[s].x)[jj];
          acc[s][0] = fmaf(as, w4.x, acc[s][0]);
          acc[s][1] = fmaf(as, w4.y, acc[s][1]);
          acc[s][2] = fmaf(as, w4.z, acc[s][2]);
          acc[s][3] = fmaf(as, w4.w, acc[s][3]);
        }
      }
    }
    *(float4*)&D[ty][c0] = make_float4(acc[0][0], acc[0][1], acc[0][2], acc[0][3]);
    *(float4*)&D[ty + 32][c0] = make_float4(acc[1][0], acc[1][1], acc[1][2], acc[1][3]);
  };

  // scores -> sP; cols cu = tx + 16u; wave-uniform chunk skip; masked cols get 0.0f
  auto score_phase = [&](int vlen) {
    if (vlen == 0) {  // softmax of all -1e6 = uniform 1/64
#pragma unroll
      for (int u = 0; u < 4; ++u) {
        sP[ty][tx + 16 * u] = 0.015625f;
        sP[ty + 32][tx + 16 * u] = 0.015625f;
      }
      return;
    }
    float acc[2][4] = {};
#pragma unroll 2
    for (int h0 = 0; h0 < S; h0 += 4) {
      float4 q4[2];
      q4[0] = *(const float4*)&sQ[ty][h0];
      q4[1] = *(const float4*)&sQ[ty + 32][h0];
      float4 wv4 = *(const float4*)&swv[h0];
#pragma unroll
      for (int u = 0; u < 4; ++u) {
        if (16 * u < vlen) {  // wave-uniform chunk skip
          float4 k4 = *(const float4*)&sK[tx + 16 * u][h0];
#pragma unroll
          for (int jj = 0; jj < 4; ++jj) {
            float kk = (&k4.x)[jj];
            float wvh = (&wv4.x)[jj];
            acc[0][u] = fmaf(tanh_term((&q4[0].x)[jj] + kk), wvh, acc[0][u]);
            acc[1][u] = fmaf(tanh_term((&q4[1].x)[jj] + kk), wvh, acc[1][u]);
          }
        }
      }
    }
#pragma unroll
    for (int u = 0; u < 4; ++u) {
      int cu = tx + 16 * u;
      sP[ty][cu] = (cu < vlen) ? acc[0][u] : 0.0f;      // zeros feed pv tail
      sP[ty + 32][cu] = (cu < vlen) ? acc[1][u] : 0.0f;
    }
  };

  // row softmax over cols < vlen: 8 lanes per row
  auto softmax_phase = [&](int vlen) {
    if (vlen == 0) return;  // already uniform
    const int row = tid >> 3, sub = tid & 7;
    float m = -3.0e38f;
#pragma unroll
    for (int k = 0; k < 8; ++k) {
      int c = sub + 8 * k;
      if (c < vlen) m = fmaxf(m, sP[row][c]);
    }
#pragma unroll
    for (int d = 1; d < 8; d <<= 1) m = fmaxf(m, __shfl_xor(m, d, 8));
    float p[8];
    float sum = 0.f;
#pragma unroll
    for (int k = 0; k < 8; ++k) {
      int c = sub + 8 * k;
      if (c < vlen) {
        p[k] = __expf(sP[row][c] - m);
        sum += p[k];
      }
    }
#pragma unroll
    for (int d = 1; d < 8; d <<= 1) sum += __shfl_xor(sum, d, 8);
    float inv = 1.0f / sum;
#pragma unroll
    for (int k = 0; k < 8; ++k) {
      int c = sub + 8 * k;
      if (c < vlen) sP[row][c] = p[k] * inv;
    }
  };

  // D[i][j] = sum_k P[i][k] * V[k][j]; k truncated to rounded vlen (zeros beyond)
  auto pv_phase = [&](const float (*V)[ST], float (*D)[ST], int vlen) {
    const int kEnd = (vlen == 0) ? S : ((vlen + 3) & ~3);
    float acc[2][4] = {};
    for (int k0 = 0; k0 < kEnd; k0 += 4) {
      float4 p4[2];
      p4[0] = *(const float4*)&sP[ty][k0];
      p4[1] = *(const float4*)&sP[ty + 32][k0];
#pragma unroll
      for (int kk = 0; kk < 4; ++kk) {
        float4 v4 = *(const float4*)&V[k0 + kk][c0];
#pragma unroll
        for (int s = 0; s < 2; ++s) {
          float ps = (&p4[s].x)[kk];
          acc[s][0] = fmaf(ps, v4.x, acc[s][0]);
          acc[s][1] = fmaf(ps, v4.y, acc[s][1]);
          acc[s][2] = fmaf(ps, v4.z, acc[s][2]);
          acc[s][3] = fmaf(ps, v4.w, acc[s][3]);
        }
      }
    }
    *(float4*)&D[ty][c0] = make_float4(acc[0][0], acc[0][1], acc[0][2], acc[0][3]);
    *(float4*)&D[ty + 32][c0] = make_float4(acc[1][0], acc[1][1], acc[1][2], acc[1][3]);
  };

  // out[h][c] = bfc[h] + sum_r Wfc[h][r]*E1[r][c] + sum_r Wfc[h][64+r]*A1[r][c]
  auto fc_phase = [&](const float (*E1)[ST], const float (*A1)[ST], float* outg) {
    float acc[2][4];
#pragma unroll
    for (int s = 0; s < 2; ++s) {
      float bv = sbfc[ty + 32 * s];
      acc[s][0] = bv; acc[s][1] = bv; acc[s][2] = bv; acc[s][3] = bv;
    }
#pragma unroll 2
    for (int r0 = 0; r0 < S; r0 += 4) {
      float4 w4[2];
      w4[0] = *(const float4*)&sWfc[ty][r0];
      w4[1] = *(const float4*)&sWfc[ty + 32][r0];
#pragma unroll
      for (int rr = 0; rr < 4; ++rr) {
        float4 e4 = *(const float4*)&E1[r0 + rr][c0];
#pragma unroll
        for (int s = 0; s < 2; ++s) {
          float ws = (&w4[s].x)[rr];
          acc[s][0] = fmaf(ws, e4.x, acc[s][0]);
          acc[s][1] = fmaf(ws, e4.y, acc[s][1]);
          acc[s][2] = fmaf(ws, e4.z, acc[s][2]);
          acc[s][3] = fmaf(ws, e4.w, acc[s][3]);
        }
      }
    }
#pragma unroll 2
    for (int r0 = 0; r0 < S; r0 += 4) {
      float4 w4[2];
      w4[0] = *(const float4*)&sWfc[ty][S + r0];
      w4[1] = *(const float4*)&sWfc[ty + 32][S + r0];
#pragma unroll
      for (int rr = 0; rr < 4; ++rr) {
        float4 e4 = *(const float4*)&A1[r0 + rr][c0];
#pragma unroll
        for (int s = 0; s < 2; ++s) {
          float ws = (&w4[s].x)[rr];
          acc[s][0] = fmaf(ws, e4.x, acc[s][0]);
          acc[s][1] = fmaf(ws, e4.y, acc[s][1]);
          acc[s][2] = fmaf(ws, e4.z, acc[s][2]);
          acc[s][3] = fmaf(ws, e4.w, acc[s][3]);
        }
      }
    }
    *(float4*)(outg + (size_t)ty * S + c0) =
        make_float4(acc[0][0], acc[0][1], acc[0][2], acc[0][3]);
    *(float4*)(outg + (size_t)(ty + 32) * S + c0) =
        make_float4(acc[1][0], acc[1][1], acc[1][2], acc[1][3]);
  };

  // ---- attention 1: q from ex, kv = ey, vlen = valid[a] ----
  // cp2 slots fill the HBM-idle edge window (non-feeders only); 4 per long
  // phase + 1 after fc -> 34 slots = 68 pairs >= 64: drain empty for non-feeders
  proj(sEx, sWqT, sQ);
  proj(sEy, sWkT, sK);
  cp2();
  cp2();
  cp2();
  cp2();
  __syncthreads();
  score_phase(validA);
  cp2();
  cp2();
  cp2();
  cp2();
  __syncthreads();
  softmax_phase(validA);
  cp2();
  cp2();
  cp2();
  cp2();
  __syncthreads();
  pv_phase(sEy, sQ, validA);  // sQ := y2x
  cp2();
  cp2();
  cp2();
  cp2();
  __syncthreads();
  fc_phase(sEx, sQ, out + (size_t)a * 4096);
  cp2();
  __syncthreads();

  // ---- attention 2: q from ey, kv = ex, vlen = valid[b] ----
  proj(sEy, sWqT, sQ);
  proj(sEx, sWkT, sK);
  cp2();
  cp2();
  cp2();
  cp2();
  __syncthreads();
  score_phase(validB);
  cp2();
  cp2();
  cp2();
  cp2();
  __syncthreads();
  softmax_phase(validB);
  cp2();
  cp2();
  cp2();
  cp2();
  __syncthreads();
  pv_phase(sEx, sQ, validB);  // sQ := x2y
  cp2();
  cp2();
  cp2();
  cp2();
  __syncthreads();
  fc_phase(sEy, sQ, out + (size_t)b * 4096);  // y written last -> wins on self-loop

  // __syncthreads drains every wave's stores; RELEASE store orders them at agent scope
  __syncthreads();
  if (tid == 0)
    __hip_atomic_store(&done[e], 1, __ATOMIC_RELEASE, __HIP_MEMORY_SCOPE_AGENT);

  // ---- finish this block's static copy range (feeders drain here) ----
  for (; g < NPAIRS; g += 2) {
    copy_pair(g);
    copy_pair(g + 1);
  }
}

extern "C" void kernel_launch(void* const* d_in, const int* in_sizes, int n_in,
                              void* d_out, int out_size, void* d_ws, size_t ws_size,
                              hipStream_t stream) {
  const float* inputs = (const float*)d_in[0];
  const int* masks = (const int*)d_in[1];
  const int* edges = (const int*)d_in[2];
  const float* Wq = (const float*)d_in[3];
  const float* Wk = (const float*)d_in[4];
  const float* wv = (const float*)d_in[5];
  const float* Wfc = (const float*)d_in[6];
  const float* bfc = (const float*)d_in[7];
  float* out = (float*)d_out;
  int* done = (int*)d_ws;                                  // 256 ints
  unsigned int* bitmap = (unsigned int*)(done + E_EDGES);  // 1024 words

  init_kernel<<<1, 1024, 0, stream>>>(edges, done, bitmap);
  fused_kernel<<<E_EDGES, NT, 0, stream>>>(inputs, masks, edges, Wq, Wk, wv, Wfc,
                                           bfc, out, done, bitmap);
}

// Round 20
// 231.300 us; speedup vs baseline: 1.1408x; 1.0089x over previous
//
#include <hip/hip_runtime.h>

#define S 64
#define ST 68    // stride (floats) for 64-col LDS tiles; rows 16B-aligned; 2-way banks free
#define STW 132  // stride for Wfc rows (128 cols + pad)
#define E_EDGES 256
#define NT 512
#define N_NODES 32768
#define NPB 128    // nodes per block (static copy range)
#define NPAIRS 64  // 2-node copy groups per block

typedef float vf4 __attribute__((ext_vector_type(4)));  // nt-builtin-compatible 16B vector

__device__ __forceinline__ float v_rcp(float x) {
  float r;
  asm("v_rcp_f32 %0, %1" : "=v"(r) : "v"(x));
  return r;
}

// tanh(x) = 1 - 2/(exp2(2*log2e*x)+1); ~1e-7 rel err, branch-free
__device__ __forceinline__ float tanh_term(float x) {
  float t = __builtin_amdgcn_exp2f(x * 2.88539008177793f);
  return fmaf(-2.0f, v_rcp(t + 1.0f), 1.0f);
}

// zero done flags, build touched-node bitmap
__global__ void init_kernel(const int* __restrict__ edges, int* __restrict__ done,
                            unsigned int* __restrict__ bitmap) {
  const int tid = threadIdx.x;  // 1024 threads, 1 block
  if (tid < E_EDGES) done[tid] = 0;
  bitmap[tid] = 0u;
  __syncthreads();
  if (tid < 2 * E_EDGES) {
    int node = edges[tid];
    atomicOr(&bitmap[node >> 5], 1u << (node & 31));
  }
}

__global__ __launch_bounds__(NT, 1) void fused_kernel(
    const float* __restrict__ inputs,
    const int* __restrict__ masks,
    const int* __restrict__ edges,
    const float* __restrict__ Wq,
    const float* __restrict__ Wk,
    const float* __restrict__ wv,
    const float* __restrict__ Wfc,
    const float* __restrict__ bfc,
    float* __restrict__ out,
    int* __restrict__ done,
    const unsigned int* __restrict__ bitmap) {
  const int tid = threadIdx.x;
  const int e = blockIdx.x;
  const int lane = tid & 63;
  const int wvid = tid >> 6;

  __shared__ float sWqT[S][ST];   // transposed: sWqT[j][h] = Wq[h][j]
  __shared__ float sWkT[S][ST];
  __shared__ float sWfc[S][STW];  // sWfc[h][r], r<128
  __shared__ float sEx[S][ST];
  __shared__ float sEy[S][ST];
  __shared__ float sQ[S][ST];
  __shared__ float sK[S][ST];
  __shared__ float sP[S][ST];
  __shared__ float swv[S];
  __shared__ float sbfc[S];
  __shared__ unsigned int sBitmap[N_NODES / 32];  // 4 KB
  __shared__ int sMeta[6];  // depA, depB, validA, validB, ready, hasSucc

  const int a = edges[e];
  const int b = edges[E_EDGES + e];

  if (tid < 2) sMeta[tid] = -1;
  if (tid == 2) sMeta[5] = 0;
  __syncthreads();
  // dep scan: latest earlier edge touching node a / node b
  // feeder scan: any LATER edge touching a or b reads our output -> release fast
  if (tid < E_EDGES) {
    int xa = edges[tid], yb = edges[E_EDGES + tid];
    bool touches = (xa == a || yb == a || xa == b || yb == b);
    if (tid < e) {
      if (xa == a || yb == a) atomicMax(&sMeta[0], tid);
      if (xa == b || yb == b) atomicMax(&sMeta[1], tid);
    } else if (tid > e && touches) {
      sMeta[5] = 1;  // benign race: all writers store 1
    }
  }

  // stage weights (transposed Wq/Wk), Wfc, wv/bfc, bitmap
#pragma unroll
  for (int k = 0; k < 2; ++k) {
    int i4 = tid + k * NT;  // 0..1023
    int h = i4 >> 4, j0 = (i4 & 15) << 2;
    float4 q4 = *(const float4*)(Wq + h * S + j0);
    float4 k4 = *(const float4*)(Wk + h * S + j0);
    sWqT[j0 + 0][h] = q4.x; sWqT[j0 + 1][h] = q4.y;
    sWqT[j0 + 2][h] = q4.z; sWqT[j0 + 3][h] = q4.w;
    sWkT[j0 + 0][h] = k4.x; sWkT[j0 + 1][h] = k4.y;
    sWkT[j0 + 2][h] = k4.z; sWkT[j0 + 3][h] = k4.w;
  }
#pragma unroll
  for (int k = 0; k < 4; ++k) {
    int i4 = tid + k * NT;  // 0..2047
    int h = i4 >> 5, r0 = (i4 & 31) << 2;
    *(float4*)&sWfc[h][r0] = *(const float4*)(Wfc + h * 2 * S + r0);
  }
  if (tid < S) { swv[tid] = wv[tid]; sbfc[tid] = bfc[tid]; }
  sBitmap[tid] = bitmap[tid];
  sBitmap[tid + NT] = bitmap[tid + NT];

  // valid lengths
  int mv = 0;
  if (wvid == 0) mv = masks[(size_t)a * S + lane];
  else if (wvid == 1) mv = masks[(size_t)b * S + lane];
#pragma unroll
  for (int d = 1; d < 64; d <<= 1) mv += __shfl_xor(mv, d, 64);
  if (tid == 0) sMeta[2] = mv;
  if (tid == 64) sMeta[3] = mv;

  __syncthreads();
  const int depA = sMeta[0], depB = sMeta[1];
  const int validA = sMeta[2], validB = sMeta[3];
  const bool feeder = sMeta[5] != 0;  // later blocks wait on us -> defer copy

  // copy pair p of this block's static range: 4 nontemporal vf4 loads over a
  // contiguous 32 KB span, tight nt stores (1x HBM writes; bitmap test uniform)
  auto copy_pair = [&](int p) {
    const int n0 = e * NPB + 2 * p;
    const int n1 = n0 + 1;
    const size_t f4 = (size_t)n0 * 1024;
    const vf4* __restrict__ src = (const vf4*)inputs + f4;
    vf4* __restrict__ dst = (vf4*)out + f4;
    vf4 v0 = __builtin_nontemporal_load(src + tid);
    vf4 v1 = __builtin_nontemporal_load(src + tid + 512);
    vf4 v2 = __builtin_nontemporal_load(src + tid + 1024);
    vf4 v3 = __builtin_nontemporal_load(src + tid + 1536);
    if (!(sBitmap[n0 >> 5] & (1u << (n0 & 31)))) {
      __builtin_nontemporal_store(v0, dst + tid);
      __builtin_nontemporal_store(v1, dst + tid + 512);
    }
    if (!(sBitmap[n1 >> 5] & (1u << (n1 & 31)))) {
      __builtin_nontemporal_store(v2, dst + tid + 1024);
      __builtin_nontemporal_store(v3, dst + tid + 1536);
    }
  };

  int g = 0;  // copy progress through this block's 64 pairs
  // boundary copy slot: feeders skip (fast done-release); others fill the
  // HBM-idle edge window with 2 tight pairs per slot
  auto cp2 = [&]() {
    if (!feeder && g < NPAIRS) {
      copy_pair(g);
      copy_pair(g + 1);
      g += 2;
    }
  };

  // dep blocks poll (RELAXED, no per-iteration invalidate); then ONE acquire per dep.
  // Feeders spin without copying (minimal chain latency); others copy while waiting.
  if (depA >= 0 || depB >= 0) {
    for (;;) {
      __syncthreads();
      if (tid == 0) {
        int ok = 1;
        if (depA >= 0 &&
            __hip_atomic_load(&done[depA], __ATOMIC_RELAXED, __HIP_MEMORY_SCOPE_AGENT) == 0)
          ok = 0;
        if (ok && depB >= 0 &&
            __hip_atomic_load(&done[depB], __ATOMIC_RELAXED, __HIP_MEMORY_SCOPE_AGENT) == 0)
          ok = 0;
        sMeta[4] = ok;
      }
      __syncthreads();
      if (sMeta[4]) break;
      if (!feeder && g < NPAIRS) {
        copy_pair(g);
        copy_pair(g + 1);
        g += 2;
      } else {
        __builtin_amdgcn_s_sleep(8);
      }
    }
    if (tid == 0) {
      if (depA >= 0)
        (void)__hip_atomic_load(&done[depA], __ATOMIC_ACQUIRE, __HIP_MEMORY_SCOPE_AGENT);
      if (depB >= 0)
        (void)__hip_atomic_load(&done[depB], __ATOMIC_ACQUIRE, __HIP_MEMORY_SCOPE_AGENT);
    }
    __syncthreads();
  }

  // stage embeddings (first touch from inputs, else chain state in out)
  const float* exg = (depA >= 0) ? out + (size_t)a * 4096 : inputs + (size_t)a * 4096;
  const float* eyg = (depB >= 0) ? out + (size_t)b * 4096 : inputs + (size_t)b * 4096;
#pragma unroll
  for (int k = 0; k < 2; ++k) {
    int i4 = tid + k * NT;
    int r = i4 >> 4, c4 = (i4 & 15) << 2;
    *(float4*)&sEx[r][c4] = *(const float4*)(exg + r * S + c4);
    *(float4*)&sEy[r][c4] = *(const float4*)(eyg + r * S + c4);
  }
  __syncthreads();

  // --- thread tiling: rows {ty, ty+32}, cols c0..c0+3 ---
  const int ty = tid >> 4;  // 0..31
  const int tx = tid & 15;  // 0..15
  const int c0 = tx << 2;

  // D[i][h] = sum_j A[i][j] * WT[j][h]
  auto proj = [&](const float (*A)[ST], const float (*WT)[ST], float (*D)[ST]) {
    float acc[2][4] = {};
#pragma unroll 4
    for (int j0 = 0; j0 < S; j0 += 4) {
      float4 av[2];
      av[0] = *(const float4*)&A[ty][j0];
      av[1] = *(const float4*)&A[ty + 32][j0];
#pragma unroll
      for (int jj = 0; jj < 4; ++jj) {
        float4 w4 = *(const float4*)&WT[j0 + jj][c0];
#pragma unroll
        for (int s = 0; s < 2; ++s) {
          float as = (&av[s].x)[jj];
          acc[s][0] = fmaf(as, w4.x, acc[s][0]);
          acc[s][1] = fmaf(as, w4.y, acc[s][1]);
          acc[s][2] = fmaf(as, w4.z, acc[s][2]);
          acc[s][3] = fmaf(as, w4.w, acc[s][3]);
        }
      }
    }
    *(float4*)&D[ty][c0] = make_float4(acc[0][0], acc[0][1], acc[0][2], acc[0][3]);
    *(float4*)&D[ty + 32][c0] = make_float4(acc[1][0], acc[1][1], acc[1][2], acc[1][3]);
  };

  // scores + FUSED softmax -> sP (normalized). Row ty's 64 cols live in the
  // 16 lanes sharing ty (tid = 16*ty + tx, aligned 16-lane group) -> row
  // max/sum reduce via __shfl_xor width 16, no LDS round trip, no barrier.
  auto score_phase = [&](int vlen) {
    if (vlen == 0) {  // softmax of all -1e6 = uniform 1/64
#pragma unroll
      for (int u = 0; u < 4; ++u) {
        sP[ty][tx + 16 * u] = 0.015625f;
        sP[ty + 32][tx + 16 * u] = 0.015625f;
      }
      return;
    }
    float acc[2][4] = {};
#pragma unroll 2
    for (int h0 = 0; h0 < S; h0 += 4) {
      float4 q4[2];
      q4[0] = *(const float4*)&sQ[ty][h0];
      q4[1] = *(const float4*)&sQ[ty + 32][h0];
      float4 wv4 = *(const float4*)&swv[h0];
#pragma unroll
      for (int u = 0; u < 4; ++u) {
        if (16 * u < vlen) {  // wave-uniform chunk skip
          float4 k4 = *(const float4*)&sK[tx + 16 * u][h0];
#pragma unroll
          for (int jj = 0; jj < 4; ++jj) {
            float kk = (&k4.x)[jj];
            float wvh = (&wv4.x)[jj];
            acc[0][u] = fmaf(tanh_term((&q4[0].x)[jj] + kk), wvh, acc[0][u]);
            acc[1][u] = fmaf(tanh_term((&q4[1].x)[jj] + kk), wvh, acc[1][u]);
          }
        }
      }
    }
    // in-register masked softmax per row (s=0: row ty, s=1: row ty+32)
#pragma unroll
    for (int s = 0; s < 2; ++s) {
      float m = -3.0e38f;
#pragma unroll
      for (int u = 0; u < 4; ++u) {
        int cu = tx + 16 * u;
        if (cu < vlen) m = fmaxf(m, acc[s][u]);
      }
#pragma unroll
      for (int d = 1; d < 16; d <<= 1) m = fmaxf(m, __shfl_xor(m, d, 16));
      float p[4];
      float sum = 0.f;
#pragma unroll
      for (int u = 0; u < 4; ++u) {
        int cu = tx + 16 * u;
        if (cu < vlen) {
          p[u] = __expf(acc[s][u] - m);
          sum += p[u];
        } else {
          p[u] = 0.0f;
        }
      }
#pragma unroll
      for (int d = 1; d < 16; d <<= 1) sum += __shfl_xor(sum, d, 16);
      float inv = 1.0f / sum;
      const int row = (s == 0) ? ty : ty + 32;
#pragma unroll
      for (int u = 0; u < 4; ++u) sP[row][tx + 16 * u] = p[u] * inv;
    }
  };

  // D[i][j] = sum_k P[i][k] * V[k][j]; k truncated to rounded vlen (zeros beyond)
  auto pv_phase = [&](const float (*V)[ST], float (*D)[ST], int vlen) {
    const int kEnd = (vlen == 0) ? S : ((vlen + 3) & ~3);
    float acc[2][4] = {};
    for (int k0 = 0; k0 < kEnd; k0 += 4) {
      float4 p4[2];
      p4[0] = *(const float4*)&sP[ty][k0];
      p4[1] = *(const float4*)&sP[ty + 32][k0];
#pragma unroll
      for (int kk = 0; kk < 4; ++kk) {
        float4 v4 = *(const float4*)&V[k0 + kk][c0];
#pragma unroll
        for (int s = 0; s < 2; ++s) {
          float ps = (&p4[s].x)[kk];
          acc[s][0] = fmaf(ps, v4.x, acc[s][0]);
          acc[s][1] = fmaf(ps, v4.y, acc[s][1]);
          acc[s][2] = fmaf(ps, v4.z, acc[s][2]);
          acc[s][3] = fmaf(ps, v4.w, acc[s][3]);
        }
      }
    }
    *(float4*)&D[ty][c0] = make_float4(acc[0][0], acc[0][1], acc[0][2], acc[0][3]);
    *(float4*)&D[ty + 32][c0] = make_float4(acc[1][0], acc[1][1], acc[1][2], acc[1][3]);
  };

  // out[h][c] = bfc[h] + sum_r Wfc[h][r]*E1[r][c] + sum_r Wfc[h][64+r]*A1[r][c]
  auto fc_phase = [&](const float (*E1)[ST], const float (*A1)[ST], float* outg) {
    float acc[2][4];
#pragma unroll
    for (int s = 0; s < 2; ++s) {
      float bv = sbfc[ty + 32 * s];
      acc[s][0] = bv; acc[s][1] = bv; acc[s][2] = bv; acc[s][3] = bv;
    }
#pragma unroll 2
    for (int r0 = 0; r0 < S; r0 += 4) {
      float4 w4[2];
      w4[0] = *(const float4*)&sWfc[ty][r0];
      w4[1] = *(const float4*)&sWfc[ty + 32][r0];
#pragma unroll
      for (int rr = 0; rr < 4; ++rr) {
        float4 e4 = *(const float4*)&E1[r0 + rr][c0];
#pragma unroll
        for (int s = 0; s < 2; ++s) {
          float ws = (&w4[s].x)[rr];
          acc[s][0] = fmaf(ws, e4.x, acc[s][0]);
          acc[s][1] = fmaf(ws, e4.y, acc[s][1]);
          acc[s][2] = fmaf(ws, e4.z, acc[s][2]);
          acc[s][3] = fmaf(ws, e4.w, acc[s][3]);
        }
      }
    }
#pragma unroll 2
    for (int r0 = 0; r0 < S; r0 += 4) {
      float4 w4[2];
      w4[0] = *(const float4*)&sWfc[ty][S + r0];
      w4[1] = *(const float4*)&sWfc[ty + 32][S + r0];
#pragma unroll
      for (int rr = 0; rr < 4; ++rr) {
        float4 e4 = *(const float4*)&A1[r0 + rr][c0];
#pragma unroll
        for (int s = 0; s < 2; ++s) {
          float ws = (&w4[s].x)[rr];
          acc[s][0] = fmaf(ws, e4.x, acc[s][0]);
          acc[s][1] = fmaf(ws, e4.y, acc[s][1]);
          acc[s][2] = fmaf(ws, e4.z, acc[s][2]);
          acc[s][3] = fmaf(ws, e4.w, acc[s][3]);
        }
      }
    }
    *(float4*)(outg + (size_t)ty * S + c0) =
        make_float4(acc[0][0], acc[0][1], acc[0][2], acc[0][3]);
    *(float4*)(outg + (size_t)(ty + 32) * S + c0) =
        make_float4(acc[1][0], acc[1][1], acc[1][2], acc[1][3]);
  };

  // ---- attention 1: q from ex, kv = ey, vlen = valid[a] ----
  // score now includes softmax (in-wave reduce) -> one less phase per attention
  proj(sEx, sWqT, sQ);
  proj(sEy, sWkT, sK);
  cp2();
  cp2();
  cp2();
  cp2();
  __syncthreads();
  score_phase(validA);
  cp2();
  cp2();
  cp2();
  cp2();
  cp2();
  __syncthreads();
  pv_phase(sEy, sQ, validA);  // sQ := y2x
  cp2();
  cp2();
  cp2();
  cp2();
  __syncthreads();
  fc_phase(sEx, sQ, out + (size_t)a * 4096);
  cp2();
  __syncthreads();

  // ---- attention 2: q from ey, kv = ex, vlen = valid[b] ----
  proj(sEy, sWqT, sQ);
  proj(sEx, sWkT, sK);
  cp2();
  cp2();
  cp2();
  cp2();
  __syncthreads();
  score_phase(validB);
  cp2();
  cp2();
  cp2();
  cp2();
  cp2();
  __syncthreads();
  pv_phase(sEx, sQ, validB);  // sQ := x2y
  cp2();
  cp2();
  cp2();
  cp2();
  __syncthreads();
  fc_phase(sEy, sQ, out + (size_t)b * 4096);  // y written last -> wins on self-loop

  // __syncthreads drains every wave's stores; RELEASE store orders them at agent scope
  __syncthreads();
  if (tid == 0)
    __hip_atomic_store(&done[e], 1, __ATOMIC_RELEASE, __HIP_MEMORY_SCOPE_AGENT);

  // ---- finish this block's static copy range (feeders drain here) ----
  for (; g < NPAIRS; g += 2) {
    copy_pair(g);
    copy_pair(g + 1);
  }
}

extern "C" void kernel_launch(void* const* d_in, const int* in_sizes, int n_in,
                              void* d_out, int out_size, void* d_ws, size_t ws_size,
                              hipStream_t stream) {
  const float* inputs = (const float*)d_in[0];
  const int* masks = (const int*)d_in[1];
  const int* edges = (const int*)d_in[2];
  const float* Wq = (const float*)d_in[3];
  const float* Wk = (const float*)d_in[4];
  const float* wv = (const float*)d_in[5];
  const float* Wfc = (const float*)d_in[6];
  const float* bfc = (const float*)d_in[7];
  float* out = (float*)d_out;
  int* done = (int*)d_ws;                                  // 256 ints
  unsigned int* bitmap = (unsigned int*)(done + E_EDGES);  // 1024 words

  init_kernel<<<1, 1024, 0, stream>>>(edges, done, bitmap);
  fused_kernel<<<E_EDGES, NT, 0, stream>>>(inputs, masks, edges, Wq, Wk, wv, Wfc,
                                           bfc, out, done, bitmap);
}